// Round 1
// baseline (199.480 us; speedup 1.0000x reference)
//
#include <hip/hip_runtime.h>

// ws layout (floats):
//   [0,64)            chan_mean
//   [64, 64+2048)     off[16 phases][64 ch][2]   (ox, oy)
//   [2112, +8192)     wcT[16][64][8]   Wc_eff transposed: [ch][k]
//   [10304, +8192)    weT[16][64][8]   We_eff: [ch][k]

__device__ __forceinline__ float relu_(float v){ return fmaxf(v, 0.f); }
__device__ __forceinline__ float sigm_(float v){ return 1.f/(1.f + __expf(-v)); }

__global__ void k_mean(const float* __restrict__ x, float* __restrict__ ws) {
  const int ch = blockIdx.x, t = threadIdx.x;
  float s = 0.f;
  for (int b = 0; b < 4; ++b) {
    const float* p = x + (size_t)(b*64 + ch)*4096;
    for (int idx = t; idx < 4096; idx += 256) s += p[idx];
  }
  __shared__ float red[256];
  red[t] = s; __syncthreads();
  for (int off = 128; off > 0; off >>= 1) {
    if (t < off) red[t] += red[t + off];
    __syncthreads();
  }
  if (t == 0) ws[ch] = red[0] * (1.f/16384.f);
}

__global__ void k_phase(const float* __restrict__ wc, const float* __restrict__ we,
    const float* __restrict__ Wb1, const float* __restrict__ bb1,
    const float* __restrict__ Wb2, const float* __restrict__ bb2,
    const float* __restrict__ Wr1, const float* __restrict__ br1,
    const float* __restrict__ Wr2, const float* __restrict__ br2,
    const float* __restrict__ Wq1, const float* __restrict__ bq1,
    const float* __restrict__ Wq2, const float* __restrict__ bq2,
    const float* __restrict__ Wq3, const float* __restrict__ bq3,
    const float* __restrict__ Wo1, const float* __restrict__ bo1,
    const float* __restrict__ Wo2, const float* __restrict__ bo2,
    const float* __restrict__ Wo3, const float* __restrict__ bo3,
    float* __restrict__ ws)
{
  const int p = blockIdx.x, pi = p >> 2, pj = p & 3;
  const int t = threadIdx.x;
  const float chv = 0.25f*pi - 0.375f, cwv = 0.25f*pj - 0.375f;

  __shared__ float meanL[64];
  __shared__ float t1L[64][4];
  __shared__ float embL[64][4];
  __shared__ float rpL[64][4];
  __shared__ float r4[4];
  __shared__ float q1L[64], q2L[64];
  __shared__ float rwL[4];
  __shared__ float oxL[64][4], oyL[64][4];

  if (t < 64) meanL[t] = ws[t];
  __syncthreads();

  if (t < 64) {  // body layer 1 over channel axis (f handled analytically: inp[:,1..3] uniform)
    float a0 = 0.f, as = 0.f;
    for (int c = 0; c < 64; ++c) { float w = Wb1[t*64+c]; a0 += w*meanL[c]; as += w; }
    float bb = bb1[t];
    t1L[t][0] = relu_(a0 + bb);
    t1L[t][1] = relu_(0.25f*as + bb);
    t1L[t][2] = relu_(chv*as + bb);
    t1L[t][3] = relu_(cwv*as + bb);
  }
  __syncthreads();
  if (t < 64) {  // body layer 2
    float bb = bb2[t];
    float e0=bb,e1=bb,e2=bb,e3=bb;
    for (int c = 0; c < 64; ++c) {
      float w = Wb2[t*64+c];
      e0 += w*t1L[c][0]; e1 += w*t1L[c][1]; e2 += w*t1L[c][2]; e3 += w*t1L[c][3];
    }
    embL[t][0]=relu_(e0); embL[t][1]=relu_(e1); embL[t][2]=relu_(e2); embL[t][3]=relu_(e3);
  }
  __syncthreads();
  if (t < 64) {  // routing_1 layer 1
    float bb = br1[t];
    float p0=bb,p1=bb,p2=bb,p3=bb;
    for (int c = 0; c < 64; ++c) {
      float w = Wr1[t*64+c];
      p0 += w*embL[c][0]; p1 += w*embL[c][1]; p2 += w*embL[c][2]; p3 += w*embL[c][3];
    }
    rpL[t][0]=relu_(p0); rpL[t][1]=relu_(p1); rpL[t][2]=relu_(p2); rpL[t][3]=relu_(p3);
  }
  __syncthreads();
  if (t < 4) {   // routing_1 layer 2 + sigmoid
    float acc = br2[0];
    for (int c = 0; c < 64; ++c) acc += Wr2[c]*rpL[c][t];
    r4[t] = sigm_(acc);
  }
  __syncthreads();
  if (t < 64) {  // routing_2 layer 1
    float acc = bq1[t];
    for (int f = 0; f < 4; ++f) acc += Wq1[t*4+f]*r4[f];
    q1L[t] = relu_(acc);
  }
  __syncthreads();
  if (t < 64) {  // routing_2 layer 2
    float acc = bq2[t];
    for (int c = 0; c < 64; ++c) acc += Wq2[t*64+c]*q1L[c];
    q2L[t] = relu_(acc);
  }
  __syncthreads();
  if (t < 4) {   // routing_2 layer 3 + sigmoid -> expert weights
    float acc = bq3[t];
    for (int c = 0; c < 64; ++c) acc += Wq3[t*64+c]*q2L[c];
    rwL[t] = sigm_(acc);
  }
  __syncthreads();

  // offset head: ch = t>>2, quarter q = t&3 handles 16 of the 64 hidden neurons
  {
    const int ch = t >> 2, q = t & 3;
    const float e0 = embL[ch][0], e1 = embL[ch][1], e2 = embL[ch][2], e3 = embL[ch][3];
    float v1[64];
    #pragma unroll
    for (int o = 0; o < 64; ++o)
      v1[o] = relu_(Wo1[o*4+0]*e0 + Wo1[o*4+1]*e1 + Wo1[o*4+2]*e2 + Wo1[o*4+3]*e3 + bo1[o]);
    float ox = 0.f, oy = 0.f;
    for (int o = q*16; o < q*16+16; ++o) {
      float acc = bo2[o];
      #pragma unroll
      for (int k = 0; k < 64; ++k) acc += Wo2[o*64+k]*v1[k];
      acc = relu_(acc);
      ox += Wo3[o]*acc;
      oy += Wo3[64+o]*acc;
    }
    oxL[ch][q] = ox; oyL[ch][q] = oy;
  }
  __syncthreads();

  float* ws_off = ws + 64;
  float* ws_wcT = ws + 2112;
  float* ws_weT = ws + 10304;
  if (t < 64) {
    ws_off[(p*64+t)*2+0] = oxL[t][0]+oxL[t][1]+oxL[t][2]+oxL[t][3] + bo3[0];
    ws_off[(p*64+t)*2+1] = oyL[t][0]+oyL[t][1]+oyL[t][2]+oyL[t][3] + bo3[1];
  }
  const float r0 = rwL[0], r1 = rwL[1], r2 = rwL[2], r3 = rwL[3];
  for (int idx = t; idx < 512; idx += 256) {
    const int ch = idx >> 3, k = idx & 7;
    // wcT[p][ch][k] = sum_e rw[e] * wc[e][k][ch]
    ws_wcT[p*512 + idx] = r0*wc[(0*8+k)*64+ch] + r1*wc[(1*8+k)*64+ch]
                        + r2*wc[(2*8+k)*64+ch] + r3*wc[(3*8+k)*64+ch];
    // weT[p][ch][k] = sum_e rw[e] * we[e][ch][k]
    ws_weT[p*512 + idx] = r0*we[(0*64+ch)*8+k] + r1*we[(1*64+ch)*8+k]
                        + r2*we[(2*64+ch)*8+k] + r3*we[(3*64+ch)*8+k];
  }
}

__launch_bounds__(256, 4)
__global__ void k_main(const float* __restrict__ x, const float* __restrict__ ws,
                       float* __restrict__ out) {
  const int i = blockIdx.x;   // output row 0..255
  const int b = blockIdx.y;   // batch 0..3
  const int j = threadIdx.x;  // output col 0..255
  const int pi = i & 3;
  const int pj = j & 3;

  // phase strides padded (520 / 68) so the 4-way ph_j fan-out hits distinct banks
  __shared__ float wcT[4*520];
  __shared__ float weT[4*520];
  __shared__ float offxL[4*68];
  __shared__ int4  rowi[256];   // [ch][pj] = {row0, row1, wy0, wy1}

  const float* wsoff = ws + 64;
  const float* wswc  = ws + 2112;
  const float* wswe  = ws + 10304;

  for (int idx = threadIdx.x; idx < 2048; idx += 256) {
    const int ph = idx >> 9, rem = idx & 511;
    wcT[ph*520 + rem] = wswc[(pi*4 + ph)*512 + rem];
    weT[ph*520 + rem] = wswe[(pi*4 + ph)*512 + rem];
  }
  {
    // y-direction bilinear state is lane-uniform per (ch, ph_j): precompute 256 combos
    const int ch = threadIdx.x >> 2, ph = threadIdx.x & 3;
    const int p = pi*4 + ph;
    const float ox = wsoff[(p*64 + ch)*2 + 0];
    const float oy = wsoff[(p*64 + ch)*2 + 1];
    offxL[ph*68 + ch] = ox;
    const float py = i*0.25f - 0.375f + oy;
    const float fy = floorf(py);
    const float wy = py - fy;
    const int y0 = (int)fy, y1 = y0 + 1;
    const int y0c = min(max(y0, 0), 63), y1c = min(max(y1, 0), 63);
    const float wy0 = ((unsigned)y0 <= 63u) ? (1.f - wy) : 0.f;  // zeros padding mask folded in
    const float wy1 = ((unsigned)y1 <= 63u) ? wy : 0.f;
    rowi[ch*4 + ph] = make_int4(ch*4096 + y0c*64, ch*4096 + y1c*64,
                                __float_as_int(wy0), __float_as_int(wy1));
  }
  __syncthreads();

  const float* __restrict__ xb = x + (size_t)b*64*4096;
  const float px0 = j*0.25f - 0.375f;

  float fea[64];
  float mid[8] = {0.f,0.f,0.f,0.f,0.f,0.f,0.f,0.f};

  #pragma unroll
  for (int ch = 0; ch < 64; ++ch) {
    const int4 ri = rowi[ch*4 + pj];
    const float px = px0 + offxL[pj*68 + ch];
    const float fx = floorf(px);
    const float wx = px - fx;
    const int x0 = (int)fx, x1 = x0 + 1;
    const int x0c = min(max(x0, 0), 63), x1c = min(max(x1, 0), 63);
    const float wx0 = ((unsigned)x0 <= 63u) ? (1.f - wx) : 0.f;
    const float wx1 = ((unsigned)x1 <= 63u) ? wx : 0.f;
    const float g00 = xb[ri.x + x0c], g01 = xb[ri.x + x1c];
    const float g10 = xb[ri.y + x0c], g11 = xb[ri.y + x1c];
    const float f0 = g00*wx0 + g01*wx1;
    const float f1 = g10*wx0 + g11*wx1;
    const float fv = f0*__int_as_float(ri.z) + f1*__int_as_float(ri.w);
    fea[ch] = fv;
    const float4* wcv = reinterpret_cast<const float4*>(&wcT[pj*520 + ch*8]);
    const float4 wa = wcv[0], wb = wcv[1];
    mid[0] += wa.x*fv; mid[1] += wa.y*fv; mid[2] += wa.z*fv; mid[3] += wa.w*fv;
    mid[4] += wb.x*fv; mid[5] += wb.y*fv; mid[6] += wb.z*fv; mid[7] += wb.w*fv;
  }

  const int obase = (b*64)*65536 + i*256 + j;
  #pragma unroll
  for (int ch = 0; ch < 64; ++ch) {
    const float4* wev = reinterpret_cast<const float4*>(&weT[pj*520 + ch*8]);
    const float4 wa = wev[0], wb = wev[1];
    float acc = fea[ch];
    acc += wa.x*mid[0] + wa.y*mid[1] + wa.z*mid[2] + wa.w*mid[3];
    acc += wb.x*mid[4] + wb.y*mid[5] + wb.z*mid[6] + wb.w*mid[7];
    out[obase + ch*65536] = acc;
  }
}

extern "C" void kernel_launch(void* const* d_in, const int* in_sizes, int n_in,
                              void* d_out, int out_size, void* d_ws, size_t ws_size,
                              hipStream_t stream) {
  const float* x   = (const float*)d_in[0];
  const float* wc  = (const float*)d_in[1];
  const float* we  = (const float*)d_in[2];
  const float* Wb1 = (const float*)d_in[3];
  const float* bb1 = (const float*)d_in[4];
  const float* Wb2 = (const float*)d_in[5];
  const float* bb2 = (const float*)d_in[6];
  const float* Wr1 = (const float*)d_in[7];
  const float* br1 = (const float*)d_in[8];
  const float* Wr2 = (const float*)d_in[9];
  const float* br2 = (const float*)d_in[10];
  const float* Wq1 = (const float*)d_in[11];
  const float* bq1 = (const float*)d_in[12];
  const float* Wq2 = (const float*)d_in[13];
  const float* bq2 = (const float*)d_in[14];
  const float* Wq3 = (const float*)d_in[15];
  const float* bq3 = (const float*)d_in[16];
  const float* Wo1 = (const float*)d_in[17];
  const float* bo1 = (const float*)d_in[18];
  const float* Wo2 = (const float*)d_in[19];
  const float* bo2 = (const float*)d_in[20];
  const float* Wo3 = (const float*)d_in[21];
  const float* bo3 = (const float*)d_in[22];
  float* ws  = (float*)d_ws;
  float* out = (float*)d_out;

  k_mean<<<64, 256, 0, stream>>>(x, ws);
  k_phase<<<16, 256, 0, stream>>>(wc, we, Wb1, bb1, Wb2, bb2, Wr1, br1, Wr2, br2,
                                  Wq1, bq1, Wq2, bq2, Wq3, bq3,
                                  Wo1, bo1, Wo2, bo2, Wo3, bo3, ws);
  k_main<<<dim3(256, 4), 256, 0, stream>>>(x, ws, out);
}

// Round 2
// 164.349 us; speedup vs baseline: 1.2138x; 1.2138x over previous
//
#include <hip/hip_runtime.h>

// ws layout (floats):
//   [0,64)            chan_mean
//   [64, 64+2048)     off[16 phases][64 ch][2]   (ox, oy)
//   [2112, +8192)     wcT[16][64][8]   Wc_eff transposed: [ch][k]
//   [10304, +8192)    weT[16][64][8]   We_eff: [ch][k]

__device__ __forceinline__ float relu_(float v){ return fmaxf(v, 0.f); }
__device__ __forceinline__ float sigm_(float v){ return 1.f/(1.f + __expf(-v)); }

__global__ void k_mean(const float* __restrict__ x, float* __restrict__ ws) {
  const int ch = blockIdx.x, t = threadIdx.x;
  float s = 0.f;
  for (int b = 0; b < 4; ++b) {
    const float4* p = reinterpret_cast<const float4*>(x + (size_t)(b*64 + ch)*4096);
    for (int idx = t; idx < 1024; idx += 256) { float4 v = p[idx]; s += (v.x+v.y)+(v.z+v.w); }
  }
  __shared__ float red[256];
  red[t] = s; __syncthreads();
  for (int off = 128; off > 0; off >>= 1) {
    if (t < off) red[t] += red[t + off];
    __syncthreads();
  }
  if (t == 0) ws[ch] = red[0] * (1.f/16384.f);
}

__launch_bounds__(256)
__global__ void k_phase(const float* __restrict__ wc, const float* __restrict__ we,
    const float* __restrict__ Wb1, const float* __restrict__ bb1,
    const float* __restrict__ Wb2, const float* __restrict__ bb2,
    const float* __restrict__ Wr1, const float* __restrict__ br1,
    const float* __restrict__ Wr2, const float* __restrict__ br2,
    const float* __restrict__ Wq1, const float* __restrict__ bq1,
    const float* __restrict__ Wq2, const float* __restrict__ bq2,
    const float* __restrict__ Wq3, const float* __restrict__ bq3,
    const float* __restrict__ Wo1, const float* __restrict__ bo1,
    const float* __restrict__ Wo2, const float* __restrict__ bo2,
    const float* __restrict__ Wo3, const float* __restrict__ bo3,
    float* __restrict__ ws)
{
  const int p = blockIdx.x, pi = p >> 2, pj = p & 3;
  const int t = threadIdx.x;
  const float chv = 0.25f*pi - 0.375f, cwv = 0.25f*pj - 0.375f;

  // LDS-staged weights: transposed for lane-conflict-free matvec stages,
  // natural for wave-uniform-broadcast offset-head rows. ~86 KB -> 1 block/CU.
  __shared__ __align__(16) float WbT1[4096];
  __shared__ __align__(16) float WbT2[4096];
  __shared__ __align__(16) float WrT1[4096];
  __shared__ __align__(16) float WqT2[4096];
  __shared__ __align__(16) float Wo2L[4096];
  __shared__ __align__(16) float Wo1L[256];
  __shared__ float Wo3L[128];
  __shared__ float bo1L[64], bo2L[64];

  __shared__ float meanL[64];
  __shared__ __align__(16) float t1L[64][4];
  __shared__ __align__(16) float embL[64][4];
  __shared__ __align__(16) float rpL[64][4];
  __shared__ float r4[4];
  __shared__ float q1L[64], q2L[64];
  __shared__ float rwL[4];
  __shared__ float oxL[64][4], oyL[64][4];

  // ---- stage weights into LDS (coalesced float4 global reads) ----
  {
    const float* srcs[4] = {Wb1, Wb2, Wr1, Wq2};
    float* dsts[4] = {WbT1, WbT2, WrT1, WqT2};
    for (int m = 0; m < 4; ++m) {
      const float4* W4 = reinterpret_cast<const float4*>(srcs[m]);
      float* WT = dsts[m];
      for (int v = t; v < 1024; v += 256) {
        float4 d = W4[v];
        int r = v >> 4, c = (v & 15) << 2;
        WT[(c+0)*64 + r] = d.x;
        WT[(c+1)*64 + r] = d.y;
        WT[(c+2)*64 + r] = d.z;
        WT[(c+3)*64 + r] = d.w;
      }
    }
    for (int v = t; v < 1024; v += 256)
      reinterpret_cast<float4*>(Wo2L)[v] = reinterpret_cast<const float4*>(Wo2)[v];
    if (t < 64) {
      reinterpret_cast<float4*>(Wo1L)[t] = reinterpret_cast<const float4*>(Wo1)[t];
      bo1L[t] = bo1[t]; bo2L[t] = bo2[t];
      meanL[t] = ws[t];
    }
    if (t >= 64 && t < 192) Wo3L[t-64] = Wo3[t-64];
  }
  __syncthreads();

  if (t < 64) {  // body layer 1 (f=1..3 analytic: inp features uniform)
    float a0 = 0.f, as = 0.f;
    #pragma unroll 8
    for (int c = 0; c < 64; ++c) { float w = WbT1[c*64+t]; a0 += w*meanL[c]; as += w; }
    float bb = bb1[t];
    t1L[t][0] = relu_(a0 + bb);
    t1L[t][1] = relu_(0.25f*as + bb);
    t1L[t][2] = relu_(chv*as + bb);
    t1L[t][3] = relu_(cwv*as + bb);
  }
  __syncthreads();
  if (t < 64) {  // body layer 2
    float bb = bb2[t];
    float e0=bb,e1=bb,e2=bb,e3=bb;
    #pragma unroll 8
    for (int c = 0; c < 64; ++c) {
      float w = WbT2[c*64+t];
      float4 tv = *reinterpret_cast<const float4*>(&t1L[c][0]);
      e0 += w*tv.x; e1 += w*tv.y; e2 += w*tv.z; e3 += w*tv.w;
    }
    embL[t][0]=relu_(e0); embL[t][1]=relu_(e1); embL[t][2]=relu_(e2); embL[t][3]=relu_(e3);
  }
  __syncthreads();
  if (t < 64) {  // routing_1 layer 1
    float bb = br1[t];
    float p0=bb,p1=bb,p2=bb,p3=bb;
    #pragma unroll 8
    for (int c = 0; c < 64; ++c) {
      float w = WrT1[c*64+t];
      float4 ev = *reinterpret_cast<const float4*>(&embL[c][0]);
      p0 += w*ev.x; p1 += w*ev.y; p2 += w*ev.z; p3 += w*ev.w;
    }
    rpL[t][0]=relu_(p0); rpL[t][1]=relu_(p1); rpL[t][2]=relu_(p2); rpL[t][3]=relu_(p3);
  }
  __syncthreads();
  if (t < 4) {   // routing_1 layer 2 + sigmoid
    float acc = br2[0];
    #pragma unroll
    for (int c = 0; c < 64; ++c) acc += Wr2[c]*rpL[c][t];
    r4[t] = sigm_(acc);
  }
  __syncthreads();
  if (t < 64) {  // routing_2 layer 1
    float acc = bq1[t];
    #pragma unroll
    for (int f = 0; f < 4; ++f) acc += Wq1[t*4+f]*r4[f];
    q1L[t] = relu_(acc);
  }
  __syncthreads();
  if (t < 64) {  // routing_2 layer 2
    float acc = bq2[t];
    #pragma unroll 8
    for (int c = 0; c < 64; ++c) acc += WqT2[c*64+t]*q1L[c];
    q2L[t] = relu_(acc);
  }
  __syncthreads();
  if (t < 4) {   // routing_2 layer 3 + sigmoid -> expert weights
    float acc = bq3[t];
    #pragma unroll
    for (int c = 0; c < 64; ++c) acc += Wq3[t*64+c]*q2L[c];
    rwL[t] = sigm_(acc);
  }
  __syncthreads();

  // offset head: ch = lane (t&63), quarter q = wave index (t>>6) -> all Wo2/Wo1
  // row addresses are wave-uniform -> LDS broadcast, conflict-free.
  {
    const int ch = t & 63, q = t >> 6;
    const float4 e = *reinterpret_cast<const float4*>(&embL[ch][0]);
    float v1[64];
    #pragma unroll
    for (int o = 0; o < 64; ++o) {
      float4 w = *reinterpret_cast<const float4*>(&Wo1L[o*4]);
      v1[o] = relu_(w.x*e.x + w.y*e.y + w.z*e.z + w.w*e.w + bo1L[o]);
    }
    float ox = 0.f, oy = 0.f;
    for (int o = q*16; o < q*16+16; ++o) {
      float acc = bo2L[o];
      const float4* row = reinterpret_cast<const float4*>(&Wo2L[o*64]);
      #pragma unroll
      for (int k = 0; k < 16; ++k) {
        float4 w = row[k];
        acc += w.x*v1[4*k+0] + w.y*v1[4*k+1] + w.z*v1[4*k+2] + w.w*v1[4*k+3];
      }
      acc = relu_(acc);
      ox += Wo3L[o]*acc;
      oy += Wo3L[64+o]*acc;
    }
    oxL[ch][q] = ox; oyL[ch][q] = oy;
  }
  __syncthreads();

  float* ws_off = ws + 64;
  float* ws_wcT = ws + 2112;
  float* ws_weT = ws + 10304;
  if (t < 64) {
    ws_off[(p*64+t)*2+0] = oxL[t][0]+oxL[t][1]+oxL[t][2]+oxL[t][3] + bo3[0];
    ws_off[(p*64+t)*2+1] = oyL[t][0]+oyL[t][1]+oyL[t][2]+oyL[t][3] + bo3[1];
  }
  const float r0 = rwL[0], r1 = rwL[1], r2 = rwL[2], r3 = rwL[3];
  for (int idx = t; idx < 512; idx += 256) {
    const int ch = idx >> 3, k = idx & 7;
    ws_wcT[p*512 + idx] = r0*wc[(0*8+k)*64+ch] + r1*wc[(1*8+k)*64+ch]
                        + r2*wc[(2*8+k)*64+ch] + r3*wc[(3*8+k)*64+ch];
    ws_weT[p*512 + idx] = r0*we[(0*64+ch)*8+k] + r1*we[(1*64+ch)*8+k]
                        + r2*we[(2*64+ch)*8+k] + r3*we[(3*64+ch)*8+k];
  }
}

__launch_bounds__(256, 4)
__global__ void k_main(const float* __restrict__ x, const float* __restrict__ ws,
                       float* __restrict__ out) {
  const int i = blockIdx.x;   // output row 0..255
  const int b = blockIdx.y;   // batch 0..3
  const int j = threadIdx.x;  // output col 0..255
  const int pi = i & 3;
  const int pj = j & 3;

  // phase strides padded (520 / 68) so the 4-way ph_j fan-out hits distinct banks
  __shared__ float wcT[4*520];
  __shared__ float weT[4*520];
  __shared__ float offxL[4*68];
  __shared__ int4  rowi[256];   // [ch][pj] = {row0, row1, wy0, wy1}

  const float* wsoff = ws + 64;
  const float* wswc  = ws + 2112;
  const float* wswe  = ws + 10304;

  for (int idx = threadIdx.x; idx < 2048; idx += 256) {
    const int ph = idx >> 9, rem = idx & 511;
    wcT[ph*520 + rem] = wswc[(pi*4 + ph)*512 + rem];
    weT[ph*520 + rem] = wswe[(pi*4 + ph)*512 + rem];
  }
  {
    // y-direction bilinear state is lane-uniform per (ch, ph_j): precompute 256 combos
    const int ch = threadIdx.x >> 2, ph = threadIdx.x & 3;
    const int p = pi*4 + ph;
    const float ox = wsoff[(p*64 + ch)*2 + 0];
    const float oy = wsoff[(p*64 + ch)*2 + 1];
    offxL[ph*68 + ch] = ox;
    const float py = i*0.25f - 0.375f + oy;
    const float fy = floorf(py);
    const float wy = py - fy;
    const int y0 = (int)fy, y1 = y0 + 1;
    const int y0c = min(max(y0, 0), 63), y1c = min(max(y1, 0), 63);
    const float wy0 = ((unsigned)y0 <= 63u) ? (1.f - wy) : 0.f;  // zeros padding mask folded in
    const float wy1 = ((unsigned)y1 <= 63u) ? wy : 0.f;
    rowi[ch*4 + ph] = make_int4(ch*4096 + y0c*64, ch*4096 + y1c*64,
                                __float_as_int(wy0), __float_as_int(wy1));
  }
  __syncthreads();

  const float* __restrict__ xb = x + (size_t)b*64*4096;
  const float px0 = j*0.25f - 0.375f;

  float fea[64];
  float mid[8] = {0.f,0.f,0.f,0.f,0.f,0.f,0.f,0.f};

  #pragma unroll
  for (int ch = 0; ch < 64; ++ch) {
    const int4 ri = rowi[ch*4 + pj];
    const float px = px0 + offxL[pj*68 + ch];
    const float fx = floorf(px);
    const float wx = px - fx;
    const int x0 = (int)fx, x1 = x0 + 1;
    const int x0c = min(max(x0, 0), 63), x1c = min(max(x1, 0), 63);
    const float wx0 = ((unsigned)x0 <= 63u) ? (1.f - wx) : 0.f;
    const float wx1 = ((unsigned)x1 <= 63u) ? wx : 0.f;
    const float g00 = xb[ri.x + x0c], g01 = xb[ri.x + x1c];
    const float g10 = xb[ri.y + x0c], g11 = xb[ri.y + x1c];
    const float f0 = g00*wx0 + g01*wx1;
    const float f1 = g10*wx0 + g11*wx1;
    const float fv = f0*__int_as_float(ri.z) + f1*__int_as_float(ri.w);
    fea[ch] = fv;
    const float4* wcv = reinterpret_cast<const float4*>(&wcT[pj*520 + ch*8]);
    const float4 wa = wcv[0], wb = wcv[1];
    mid[0] += wa.x*fv; mid[1] += wa.y*fv; mid[2] += wa.z*fv; mid[3] += wa.w*fv;
    mid[4] += wb.x*fv; mid[5] += wb.y*fv; mid[6] += wb.z*fv; mid[7] += wb.w*fv;
  }

  const int obase = (b*64)*65536 + i*256 + j;
  #pragma unroll
  for (int ch = 0; ch < 64; ++ch) {
    const float4* wev = reinterpret_cast<const float4*>(&weT[pj*520 + ch*8]);
    const float4 wa = wev[0], wb = wev[1];
    float acc = fea[ch];
    acc += wa.x*mid[0] + wa.y*mid[1] + wa.z*mid[2] + wa.w*mid[3];
    acc += wb.x*mid[4] + wb.y*mid[5] + wb.z*mid[6] + wb.w*mid[7];
    out[obase + ch*65536] = acc;
  }
}

extern "C" void kernel_launch(void* const* d_in, const int* in_sizes, int n_in,
                              void* d_out, int out_size, void* d_ws, size_t ws_size,
                              hipStream_t stream) {
  const float* x   = (const float*)d_in[0];
  const float* wc  = (const float*)d_in[1];
  const float* we  = (const float*)d_in[2];
  const float* Wb1 = (const float*)d_in[3];
  const float* bb1 = (const float*)d_in[4];
  const float* Wb2 = (const float*)d_in[5];
  const float* bb2 = (const float*)d_in[6];
  const float* Wr1 = (const float*)d_in[7];
  const float* br1 = (const float*)d_in[8];
  const float* Wr2 = (const float*)d_in[9];
  const float* br2 = (const float*)d_in[10];
  const float* Wq1 = (const float*)d_in[11];
  const float* bq1 = (const float*)d_in[12];
  const float* Wq2 = (const float*)d_in[13];
  const float* bq2 = (const float*)d_in[14];
  const float* Wq3 = (const float*)d_in[15];
  const float* bq3 = (const float*)d_in[16];
  const float* Wo1 = (const float*)d_in[17];
  const float* bo1 = (const float*)d_in[18];
  const float* Wo2 = (const float*)d_in[19];
  const float* bo2 = (const float*)d_in[20];
  const float* Wo3 = (const float*)d_in[21];
  const float* bo3 = (const float*)d_in[22];
  float* ws  = (float*)d_ws;
  float* out = (float*)d_out;

  k_mean<<<64, 256, 0, stream>>>(x, ws);
  k_phase<<<16, 256, 0, stream>>>(wc, we, Wb1, bb1, Wb2, bb2, Wr1, br1, Wr2, br2,
                                  Wq1, bq1, Wq2, bq2, Wq3, bq3,
                                  Wo1, bo1, Wo2, bo2, Wo3, bo3, ws);
  k_main<<<dim3(256, 4), 256, 0, stream>>>(x, ws, out);
}

// Round 3
// 160.837 us; speedup vs baseline: 1.2403x; 1.0218x over previous
//
#include <hip/hip_runtime.h>

// ws layout (floats):
//   [0,64)            chan_mean (unused now, kept for layout stability)
//   [64, 64+2048)     off[16 phases][64 ch][2]   (ox, oy)
//   [2112, +8192)     wcT[16][64][8]   Wc_eff transposed: [ch][k]
//   [10304, +8192)    weT[16][64][8]   We_eff: [ch][k]
//   [18496, +256)     mean partial sums [b][ch]

__device__ __forceinline__ float relu_(float v){ return fmaxf(v, 0.f); }
__device__ __forceinline__ float sigm_(float v){ return 1.f/(1.f + __expf(-v)); }

__global__ void k_mean(const float* __restrict__ x, float* __restrict__ ws) {
  const int ch = blockIdx.x, b = blockIdx.y, t = threadIdx.x;
  const float4* p = reinterpret_cast<const float4*>(x + (size_t)(b*64 + ch)*4096);
  float4 v0 = p[t], v1 = p[t+256], v2 = p[t+512], v3 = p[t+768];
  float s = ((v0.x+v0.y)+(v0.z+v0.w)) + ((v1.x+v1.y)+(v1.z+v1.w))
          + ((v2.x+v2.y)+(v2.z+v2.w)) + ((v3.x+v3.y)+(v3.z+v3.w));
  __shared__ float red[256];
  red[t] = s; __syncthreads();
  for (int off = 128; off > 0; off >>= 1) {
    if (t < off) red[t] += red[t + off];
    __syncthreads();
  }
  if (t == 0) ws[18496 + b*64 + ch] = red[0];
}

__launch_bounds__(256)
__global__ void k_phase(const float* __restrict__ wc, const float* __restrict__ we,
    const float* __restrict__ Wb1, const float* __restrict__ bb1,
    const float* __restrict__ Wb2, const float* __restrict__ bb2,
    const float* __restrict__ Wr1, const float* __restrict__ br1,
    const float* __restrict__ Wr2, const float* __restrict__ br2,
    const float* __restrict__ Wq1, const float* __restrict__ bq1,
    const float* __restrict__ Wq2, const float* __restrict__ bq2,
    const float* __restrict__ Wq3, const float* __restrict__ bq3,
    const float* __restrict__ Wo1, const float* __restrict__ bo1,
    const float* __restrict__ Wo2, const float* __restrict__ bo2,
    const float* __restrict__ Wo3, const float* __restrict__ bo3,
    float* __restrict__ ws)
{
  const int p = blockIdx.x, pi = p >> 2, pj = p & 3;
  const int t = threadIdx.x;
  const float chv = 0.25f*pi - 0.375f, cwv = 0.25f*pj - 0.375f;

  // Natural-orientation staging, leading dim padded 64->66: matvec reads
  // W[t*66+c] hit banks (2t+c)%32 -> 2-way aliasing, which is free (m136).
  __shared__ float WbL1[64*66];
  __shared__ float WbL2[64*66];
  __shared__ float WrL1[64*66];
  __shared__ float WqL2[64*66];
  __shared__ __align__(16) float Wo2L[4096];
  __shared__ __align__(16) float Wo1L[256];
  __shared__ __align__(16) float wcL[2048];
  __shared__ __align__(16) float weL[2048];
  __shared__ float Wo3L[128];
  __shared__ float Wq1L[256], Wq3L[256];
  __shared__ float Wr2L[64];
  __shared__ float bb1L[64], bb2L[64], br1L[64], bq1L[64], bq2L[64];
  __shared__ float bo1L[64], bo2L[64];

  __shared__ float meanL[64];
  __shared__ __align__(16) float t1L[64][4];
  __shared__ __align__(16) float embL[64][4];
  __shared__ __align__(16) float rpL[64][4];
  __shared__ float r4[4];
  __shared__ float q1L[64], q2L[64];
  __shared__ float rwL[4];
  __shared__ float oxL[64][4], oyL[64][4];

  // ---- stage EVERYTHING into LDS upfront (coalesced; overlapped latency) ----
  {
    const float* srcs[4] = {Wb1, Wb2, Wr1, Wq2};
    float* dsts[4] = {WbL1, WbL2, WrL1, WqL2};
    for (int m = 0; m < 4; ++m) {
      const float4* W4 = reinterpret_cast<const float4*>(srcs[m]);
      float* WL = dsts[m];
      for (int v = t; v < 1024; v += 256) {
        float4 d = W4[v];
        const int r = v >> 4, c = (v & 15) << 2;
        float* q = &WL[r*66 + c];
        q[0] = d.x; q[1] = d.y; q[2] = d.z; q[3] = d.w;
      }
    }
    for (int v = t; v < 1024; v += 256)
      reinterpret_cast<float4*>(Wo2L)[v] = reinterpret_cast<const float4*>(Wo2)[v];
    for (int v = t; v < 512; v += 256) {
      reinterpret_cast<float4*>(wcL)[v] = reinterpret_cast<const float4*>(wc)[v];
      reinterpret_cast<float4*>(weL)[v] = reinterpret_cast<const float4*>(we)[v];
    }
    if (t < 64) {
      reinterpret_cast<float4*>(Wo1L)[t] = reinterpret_cast<const float4*>(Wo1)[t];
      reinterpret_cast<float4*>(Wq1L)[t] = reinterpret_cast<const float4*>(Wq1)[t];
      reinterpret_cast<float4*>(Wq3L)[t] = reinterpret_cast<const float4*>(Wq3)[t];
      bb1L[t] = bb1[t]; bb2L[t] = bb2[t]; br1L[t] = br1[t];
      bq1L[t] = bq1[t]; bq2L[t] = bq2[t];
      bo1L[t] = bo1[t]; bo2L[t] = bo2[t];
      Wr2L[t] = Wr2[t];
      const float* wsp = ws + 18496;
      meanL[t] = (wsp[t] + wsp[64+t] + wsp[128+t] + wsp[192+t]) * (1.f/16384.f);
    }
    if (t >= 64 && t < 192) Wo3L[t-64] = Wo3[t-64];
  }
  __syncthreads();

  if (t < 64) {  // body layer 1 (f=1..3 analytic: inp features uniform)
    float a0 = 0.f, as = 0.f;
    const float* row = &WbL1[t*66];
    #pragma unroll 8
    for (int c = 0; c < 64; ++c) { float w = row[c]; a0 += w*meanL[c]; as += w; }
    float bb = bb1L[t];
    t1L[t][0] = relu_(a0 + bb);
    t1L[t][1] = relu_(0.25f*as + bb);
    t1L[t][2] = relu_(chv*as + bb);
    t1L[t][3] = relu_(cwv*as + bb);
  }
  __syncthreads();
  if (t < 64) {  // body layer 2
    float bb = bb2L[t];
    float e0=bb,e1=bb,e2=bb,e3=bb;
    const float* row = &WbL2[t*66];
    #pragma unroll 8
    for (int c = 0; c < 64; ++c) {
      float w = row[c];
      float4 tv = *reinterpret_cast<const float4*>(&t1L[c][0]);
      e0 += w*tv.x; e1 += w*tv.y; e2 += w*tv.z; e3 += w*tv.w;
    }
    embL[t][0]=relu_(e0); embL[t][1]=relu_(e1); embL[t][2]=relu_(e2); embL[t][3]=relu_(e3);
  }
  __syncthreads();
  if (t < 64) {  // routing_1 layer 1
    float bb = br1L[t];
    float p0=bb,p1=bb,p2=bb,p3=bb;
    const float* row = &WrL1[t*66];
    #pragma unroll 8
    for (int c = 0; c < 64; ++c) {
      float w = row[c];
      float4 ev = *reinterpret_cast<const float4*>(&embL[c][0]);
      p0 += w*ev.x; p1 += w*ev.y; p2 += w*ev.z; p3 += w*ev.w;
    }
    rpL[t][0]=relu_(p0); rpL[t][1]=relu_(p1); rpL[t][2]=relu_(p2); rpL[t][3]=relu_(p3);
  }
  __syncthreads();
  if (t < 4) {   // routing_1 layer 2 + sigmoid
    float acc = br2[0];
    #pragma unroll 8
    for (int c = 0; c < 64; ++c) acc += Wr2L[c]*rpL[c][t];
    r4[t] = sigm_(acc);
  }
  __syncthreads();
  if (t < 64) {  // routing_2 layer 1
    float acc = bq1L[t];
    #pragma unroll
    for (int f = 0; f < 4; ++f) acc += Wq1L[t*4+f]*r4[f];
    q1L[t] = relu_(acc);
  }
  __syncthreads();
  if (t < 64) {  // routing_2 layer 2
    float acc = bq2L[t];
    const float* row = &WqL2[t*66];
    #pragma unroll 8
    for (int c = 0; c < 64; ++c) acc += row[c]*q1L[c];
    q2L[t] = relu_(acc);
  }
  __syncthreads();
  if (t < 4) {   // routing_2 layer 3 + sigmoid -> expert weights
    float acc = bq3[t];
    #pragma unroll 8
    for (int c = 0; c < 64; ++c) acc += Wq3L[t*64+c]*q2L[c];
    rwL[t] = sigm_(acc);
  }
  __syncthreads();

  // offset head: ch = lane (t&63), quarter q = wave index (t>>6) -> all Wo2/Wo1
  // row addresses are wave-uniform -> LDS broadcast, conflict-free.
  {
    const int ch = t & 63, q = t >> 6;
    const float4 e = *reinterpret_cast<const float4*>(&embL[ch][0]);
    float v1[64];
    #pragma unroll
    for (int o = 0; o < 64; ++o) {
      float4 w = *reinterpret_cast<const float4*>(&Wo1L[o*4]);
      v1[o] = relu_(w.x*e.x + w.y*e.y + w.z*e.z + w.w*e.w + bo1L[o]);
    }
    float ox = 0.f, oy = 0.f;
    for (int o = q*16; o < q*16+16; ++o) {
      float acc = bo2L[o];
      const float4* row = reinterpret_cast<const float4*>(&Wo2L[o*64]);
      #pragma unroll
      for (int k = 0; k < 16; ++k) {
        float4 w = row[k];
        acc += w.x*v1[4*k+0] + w.y*v1[4*k+1] + w.z*v1[4*k+2] + w.w*v1[4*k+3];
      }
      acc = relu_(acc);
      ox += Wo3L[o]*acc;
      oy += Wo3L[64+o]*acc;
    }
    oxL[ch][q] = ox; oyL[ch][q] = oy;
  }
  __syncthreads();

  float* ws_off = ws + 64;
  float* ws_wcT = ws + 2112;
  float* ws_weT = ws + 10304;
  if (t < 64) {
    ws_off[(p*64+t)*2+0] = oxL[t][0]+oxL[t][1]+oxL[t][2]+oxL[t][3] + bo3[0];
    ws_off[(p*64+t)*2+1] = oyL[t][0]+oyL[t][1]+oyL[t][2]+oyL[t][3] + bo3[1];
  }
  const float r0 = rwL[0], r1 = rwL[1], r2 = rwL[2], r3 = rwL[3];
  for (int idx = t; idx < 512; idx += 256) {
    const int ch = idx >> 3, k = idx & 7;
    ws_wcT[p*512 + idx] = r0*wcL[(0*8+k)*64+ch] + r1*wcL[(1*8+k)*64+ch]
                        + r2*wcL[(2*8+k)*64+ch] + r3*wcL[(3*8+k)*64+ch];
    ws_weT[p*512 + idx] = r0*weL[(0*64+ch)*8+k] + r1*weL[(1*64+ch)*8+k]
                        + r2*weL[(2*64+ch)*8+k] + r3*weL[(3*64+ch)*8+k];
  }
}

// (256,3): ~170 VGPR budget so the fully-unrolled gather loop (fea[64]+mid[8]
// + pipelined load temps) fits without spills; 3 blocks/CU.
__launch_bounds__(256, 3)
__global__ void k_main(const float* __restrict__ x, const float* __restrict__ ws,
                       float* __restrict__ out) {
  const int i = blockIdx.x;   // output row 0..255
  const int b = blockIdx.y;   // batch 0..3
  const int j = threadIdx.x;  // output col 0..255
  const int pi = i & 3;
  const int pj = j & 3;

  // phase strides padded (520 / 68) so the 4-way ph_j fan-out hits distinct banks
  __shared__ float wcT[4*520];
  __shared__ float weT[4*520];
  __shared__ float offxL[4*68];
  __shared__ int4  rowi[256];   // [ch][pj] = {row0, row1, wy0, wy1}

  const float* wsoff = ws + 64;
  const float* wswc  = ws + 2112;
  const float* wswe  = ws + 10304;

  for (int idx = threadIdx.x; idx < 2048; idx += 256) {
    const int ph = idx >> 9, rem = idx & 511;
    wcT[ph*520 + rem] = wswc[(pi*4 + ph)*512 + rem];
    weT[ph*520 + rem] = wswe[(pi*4 + ph)*512 + rem];
  }
  {
    // y-direction bilinear state is lane-uniform per (ch, ph_j): precompute 256 combos
    const int ch = threadIdx.x >> 2, ph = threadIdx.x & 3;
    const int p = pi*4 + ph;
    const float ox = wsoff[(p*64 + ch)*2 + 0];
    const float oy = wsoff[(p*64 + ch)*2 + 1];
    offxL[ph*68 + ch] = ox;
    const float py = i*0.25f - 0.375f + oy;
    const float fy = floorf(py);
    const float wy = py - fy;
    const int y0 = (int)fy, y1 = y0 + 1;
    const int y0c = min(max(y0, 0), 63), y1c = min(max(y1, 0), 63);
    const float wy0 = ((unsigned)y0 <= 63u) ? (1.f - wy) : 0.f;  // zeros padding mask folded in
    const float wy1 = ((unsigned)y1 <= 63u) ? wy : 0.f;
    rowi[ch*4 + ph] = make_int4(ch*4096 + y0c*64, ch*4096 + y1c*64,
                                __float_as_int(wy0), __float_as_int(wy1));
  }
  __syncthreads();

  const float* __restrict__ xb = x + (size_t)b*64*4096;
  const float px0 = j*0.25f - 0.375f;

  float fea[64];
  float mid[8] = {0.f,0.f,0.f,0.f,0.f,0.f,0.f,0.f};

  const float4* wc_pj = reinterpret_cast<const float4*>(&wcT[pj*520]);
  const float* offx_pj = &offxL[pj*68];
  const int4* rowi_pj = &rowi[pj];

  #pragma unroll
  for (int ch = 0; ch < 64; ++ch) {
    const int4 ri = rowi_pj[ch*4];
    const float px = px0 + offx_pj[ch];
    const float fx = floorf(px);
    const float wx = px - fx;
    const int x0 = (int)fx, x1 = x0 + 1;
    const int x0c = min(max(x0, 0), 63), x1c = min(max(x1, 0), 63);
    const float wx0 = ((unsigned)x0 <= 63u) ? (1.f - wx) : 0.f;
    const float wx1 = ((unsigned)x1 <= 63u) ? wx : 0.f;
    const float g00 = xb[ri.x + x0c], g01 = xb[ri.x + x1c];
    const float g10 = xb[ri.y + x0c], g11 = xb[ri.y + x1c];
    const float f0 = g00*wx0 + g01*wx1;
    const float f1 = g10*wx0 + g11*wx1;
    const float fv = f0*__int_as_float(ri.z) + f1*__int_as_float(ri.w);
    fea[ch] = fv;
    const float4 wa = wc_pj[ch*2], wb = wc_pj[ch*2+1];
    mid[0] += wa.x*fv; mid[1] += wa.y*fv; mid[2] += wa.z*fv; mid[3] += wa.w*fv;
    mid[4] += wb.x*fv; mid[5] += wb.y*fv; mid[6] += wb.z*fv; mid[7] += wb.w*fv;
  }

  const float4* we_pj = reinterpret_cast<const float4*>(&weT[pj*520]);
  float* op = out + (size_t)(b*64)*65536 + i*256 + j;
  #pragma unroll
  for (int ch = 0; ch < 64; ++ch) {
    const float4 wa = we_pj[ch*2], wb = we_pj[ch*2+1];
    float acc = fea[ch];
    acc += wa.x*mid[0] + wa.y*mid[1] + wa.z*mid[2] + wa.w*mid[3];
    acc += wb.x*mid[4] + wb.y*mid[5] + wb.z*mid[6] + wb.w*mid[7];
    op[ch*65536] = acc;
  }
}

extern "C" void kernel_launch(void* const* d_in, const int* in_sizes, int n_in,
                              void* d_out, int out_size, void* d_ws, size_t ws_size,
                              hipStream_t stream) {
  const float* x   = (const float*)d_in[0];
  const float* wc  = (const float*)d_in[1];
  const float* we  = (const float*)d_in[2];
  const float* Wb1 = (const float*)d_in[3];
  const float* bb1 = (const float*)d_in[4];
  const float* Wb2 = (const float*)d_in[5];
  const float* bb2 = (const float*)d_in[6];
  const float* Wr1 = (const float*)d_in[7];
  const float* br1 = (const float*)d_in[8];
  const float* Wr2 = (const float*)d_in[9];
  const float* br2 = (const float*)d_in[10];
  const float* Wq1 = (const float*)d_in[11];
  const float* bq1 = (const float*)d_in[12];
  const float* Wq2 = (const float*)d_in[13];
  const float* bq2 = (const float*)d_in[14];
  const float* Wq3 = (const float*)d_in[15];
  const float* bq3 = (const float*)d_in[16];
  const float* Wo1 = (const float*)d_in[17];
  const float* bo1 = (const float*)d_in[18];
  const float* Wo2 = (const float*)d_in[19];
  const float* bo2 = (const float*)d_in[20];
  const float* Wo3 = (const float*)d_in[21];
  const float* bo3 = (const float*)d_in[22];
  float* ws  = (float*)d_ws;
  float* out = (float*)d_out;

  k_mean<<<dim3(64, 4), 256, 0, stream>>>(x, ws);
  k_phase<<<16, 256, 0, stream>>>(wc, we, Wb1, bb1, Wb2, bb2, Wr1, br1, Wr2, br2,
                                  Wq1, bq1, Wq2, bq2, Wq3, bq3,
                                  Wo1, bo1, Wo2, bo2, Wo3, bo3, ws);
  k_main<<<dim3(256, 4), 256, 0, stream>>>(x, ws, out);
}